// Round 10
// baseline (117.719 us; speedup 1.0000x reference)
//
#include <hip/hip_runtime.h>
#include <hip/hip_fp16.h>
#include <math.h>

#define HP   2080          // padded height (2048 + 2*16)
#define WP   2080          // padded width
#define MARG 16
#define HOUT 2048
#define WOUT 2048
#define RAD  16            // truncation radius; tail mass ~2e-7

#define TGRID 32           // 32x32 output tiles of 64x64
#define NBIN  1024         // one bin per output tile
#define CAP   2560         // records per tile (mean ~2248, +6.6 sigma)

// scatter shape: 256 blocks = 1/CU, ~9.4K records/block -> per-(block,bin)
// runs ~9.2 records = 74B
#define NBLK 256
#define THR  1024
#define PPT  4             // 256*1024*4 = 1,048,576 >= N
#define RCAP 10240         // per-block record slots (mean ~9410, +18 sigma)

#define AST  97            // f32 frame stride (96 + 1 pad)
#define INV  0xffffffffu

// quad-parity u64 frame offsets (cells = 4 x Q5.11 u16 fields)
#define IAA 0              // aligned rows x aligned cols: 48x48
#define IAS 2304           // aligned rows x shifted cols: 48x49
#define ISA 4656           // shifted rows x aligned cols: 49x48
#define ISS 7008           // shifted rows x shifted cols: 49x49  (total 9409)
#define QSZ 9412           // padded to uint4 multiple

#define QSCALE 2048.0f               // Q5.11
#define QINV   4.8828125e-4f         // 1/2048

// exact discrete tap via Poisson summation: g[n] = sqrt(pi/200)*exp(-pi^2 n^2/200)
__device__ __forceinline__ void make_weights(float* wreg) {
#pragma unroll
    for (int t = 0; t <= RAD; ++t)
        wreg[t] = 0.12533141373155003f * __expf(-0.04934802200544679f * (float)(t * t));
}

// ---------------------------------------------------------------------------
// pass 1: duplicate each point into every output tile whose 96x96 conv frame
// it touches; histogram atomicAdd return value IS the rank (registers,
// statically indexed); global cursor reservation issued BEFORE the scan so
// its fabric latency hides under the scan; LDS-sort by bin; coalesced
// copy-out in ~74B runs.
// ---------------------------------------------------------------------------
__global__ __launch_bounds__(THR) void scatter_kernel(const float2* __restrict__ pos,
                                                      const float* __restrict__ inten,
                                                      int* __restrict__ cursor,   // [NBIN], zeroed
                                                      ushort4* __restrict__ bins,
                                                      int n) {
    __shared__ int     lhist[NBIN];
    __shared__ int     lofs[NBIN];
    __shared__ int     lbase[NBIN];
    __shared__ int     wsum[16];
    __shared__ int     stot;
    __shared__ ushort4 lrec[RCAP];   // 80 KB
    __shared__ ushort  lbin[RCAP];   // 20 KB

    const int tid = threadIdx.x;
    lhist[tid] = 0;                  // THR == NBIN
    __syncthreads();

    const int stride = NBLK * THR;
    const int start  = blockIdx.x * THR + tid;
    unsigned ra[PPT], rb[PPT], rc[PPT];
    unsigned p0[PPT], p1[PPT], p2[PPT], p3[PPT];   // (bin<<16)|rank, statically indexed

#pragma unroll
    for (int it = 0; it < PPT; ++it) {
        int i = start + it * stride;
        p0[it] = p1[it] = p2[it] = p3[it] = INV;
        ra[it] = 0;
        if (i < n) {
            float2 p = pos[i];
            float I  = inten[i];
            float px = p.x + MARG, py = p.y + MARG;
            int col = (int)floorf(px), row = (int)floorf(py);
            row = min(max(row, 0), HP - 1);
            col = min(max(col, 0), WP - 1);
            float dy = py - (float)row, dx = px - (float)col;
            ra[it] = ((unsigned)row << 12) | (unsigned)col;
            rb[it] = (unsigned)__half_as_ushort(__float2half(dx))
                   | ((unsigned)__half_as_ushort(__float2half(dy)) << 16);
            rc[it] = (unsigned)__half_as_ushort(__float2half(I));
            int tIlo = max(0, ((row + 32) >> 6) - 1), tIhi = min(TGRID - 1, (row + 1) >> 6);
            int tJlo = max(0, ((col + 32) >> 6) - 1), tJhi = min(TGRID - 1, (col + 1) >> 6);
            int b00 = (tIlo << 5) | tJlo;
            p0[it] = ((unsigned)b00 << 16) | (unsigned)atomicAdd(&lhist[b00], 1);
            if (tJhi > tJlo) {
                int b = (tIlo << 5) | tJhi;
                p1[it] = ((unsigned)b << 16) | (unsigned)atomicAdd(&lhist[b], 1);
            }
            if (tIhi > tIlo) {
                int b = (tIhi << 5) | tJlo;
                p2[it] = ((unsigned)b << 16) | (unsigned)atomicAdd(&lhist[b], 1);
                if (tJhi > tJlo) {
                    int b2 = (tIhi << 5) | tJhi;
                    p3[it] = ((unsigned)b2 << 16) | (unsigned)atomicAdd(&lhist[b2], 1);
                }
            }
        }
    }
    __syncthreads();

    // ---- global reservation FIRST (latency hides under the scan) ----
    int c = lhist[tid];
    int gbase = (c > 0) ? atomicAdd(&cursor[tid], c) : 0;

    // ---- exclusive scan, exactly 1 bin per thread ----
    int incl = c;
    for (int d = 1; d < 64; d <<= 1) {
        int u = __shfl_up(incl, d, 64);
        if ((tid & 63) >= d) incl += u;
    }
    if ((tid & 63) == 63) wsum[tid >> 6] = incl;
    __syncthreads();
    if (tid == 0) {
        int s = 0;
        for (int w = 0; w < 16; ++w) { int x = wsum[w]; wsum[w] = s; s += x; }
        stot = s;
    }
    __syncthreads();
    lofs[tid]  = incl - c + wsum[tid >> 6];
    lbase[tid] = gbase;
    __syncthreads();

    // ---- place records into LDS by bin using the saved ranks (no atomics) ----
#pragma unroll
    for (int it = 0; it < PPT; ++it) {
        const int row = (int)(ra[it] >> 12), col = (int)(ra[it] & 4095u);
        ushort4 rec;
        rec.y = (unsigned short)(rb[it] & 0xffffu);
        rec.z = (unsigned short)(rb[it] >> 16);
        rec.w = (unsigned short)rc[it];
        auto place = [&](unsigned pv) {
            if (pv != INV) {
                int bin  = (int)(pv >> 16);
                int rank = (int)(pv & 0xffffu);
                int fr1  = row - ((bin >> 5) << 6) + 1;   // 0..96
                int fc1  = col - ((bin & 31) << 6) + 1;   // 0..96
                int slot = lofs[bin] + rank;
                if (slot < RCAP) {
                    rec.x = (unsigned short)((fr1 << 7) | fc1);
                    lrec[slot] = rec;
                    lbin[slot] = (unsigned short)bin;
                }
            }
        };
        place(p0[it]); place(p1[it]); place(p2[it]); place(p3[it]);
    }
    __syncthreads();

    // ---- coalesced copy-out ----
    const int total = min(stot, RCAP);
    for (int j = tid; j < total; j += THR) {
        int b = lbin[j];
        int g = lbase[b] + (j - lofs[b]);
        if (g < CAP) bins[(size_t)b * CAP + g] = lrec[j];
    }
}

// ---------------------------------------------------------------------------
// pass 2 (fused splat + conv, QUAD-parity u64 splat -> ONE atomic/record):
// a record's 2x2 tap block spans one row-pair (fr1-1,fr1) and one col-pair
// (fc1-1,fc1). Four parity frames (aligned/shifted rows x aligned/shifted
// cols) make that block exactly ONE u64 cell = 4 x Q5.11 u16 fields
// [tl | tr<<16 | bl<<32 | br<<48]. Frame select: (fr1&1, fc1&1); index
// fr1>>1, fc1>>1 in both parities. Phantom edge slots (rows -1/96, cols
// -1/96) absorb out-of-frame taps and are never merged -> no masking.
// Per-field accumulation < 2^16 guaranteed (lambda~0.25 taps/px/field).
// Merge: per pixel-pair, 6 u64 reads -> 2 f32 (register-staged, one
// barrier), then hconv in place + vconv + store (round-8 verbatim).
// ---------------------------------------------------------------------------
__device__ __forceinline__ void splat_rec(ushort4 r, unsigned long long* Q) {
    int fr1 = r.x >> 7, fc1 = r.x & 127;              // 0..96 each
    float dx = __half2float(__ushort_as_half(r.y));
    float dy = __half2float(__ushort_as_half(r.z));
    float I  = __half2float(__ushort_as_half(r.w));
    float wy1 = dy * I, wy0 = I - wy1;
    float wx1 = dx, wx0 = 1.0f - dx;
    unsigned f00 = (unsigned)(wy0 * wx0 * QSCALE + 0.5f);   // (row-low, col-low)
    unsigned f01 = (unsigned)(wy0 * wx1 * QSCALE + 0.5f);   // (row-low, col-high)
    unsigned f10 = (unsigned)(wy1 * wx0 * QSCALE + 0.5f);   // (row-high, col-low)
    unsigned f11 = (unsigned)(wy1 * wx1 * QSCALE + 0.5f);   // (row-high, col-high)
    unsigned long long v = (unsigned long long)(f00 | (f01 << 16))
                         | ((unsigned long long)(f10 | (f11 << 16)) << 32);
    int R = fr1 >> 1, C = fc1 >> 1;
    int idx;
    if (fr1 & 1) idx = (fc1 & 1) ? (IAA + R * 48 + C) : (IAS + R * 49 + C);
    else         idx = (fc1 & 1) ? (ISA + R * 48 + C) : (ISS + R * 49 + C);
    atomicAdd(&Q[idx], v);
}

__global__ __launch_bounds__(1024) void splat_conv(const ushort4* __restrict__ bins,
                                                   const int* __restrict__ cursor,
                                                   float* __restrict__ out) {
    __shared__ unsigned long long Q[QSZ];   // 75.3 KB quad-parity frames
    float* A = (float*)Q;                   // merged f32 frame [96][AST]
    const int tid = threadIdx.x;
    const int b  = blockIdx.x;
    const int tI = b >> 5, tJ = b & 31;

    // prefetch this tile's records (<=3/thread) BEFORE zeroing
    const int cnt = min(cursor[b], CAP);
    const ushort4* bp = bins + (size_t)b * CAP;
    const bool h0 = tid < cnt, h1 = tid + 1024 < cnt, h2 = tid + 2048 < cnt;
    ushort4 r0_ = {0,0,0,0}, r1_ = {0,0,0,0}, r2_ = {0,0,0,0};
    if (h0) r0_ = bp[tid];
    if (h1) r1_ = bp[tid + 1024];
    if (h2) r2_ = bp[tid + 2048];

    uint4* U4 = (uint4*)Q;                  // 9412 u64 = 4706 uint4
    for (int i = tid; i < 4706; i += 1024) U4[i] = make_uint4(0u, 0u, 0u, 0u);
    __syncthreads();

    if (h0) splat_rec(r0_, Q);
    if (h1) splat_rec(r1_, Q);
    if (h2) splat_rec(r2_, Q);
    __syncthreads();

    // ---- merge quad parities -> f32 frame (in place, register-staged) ----
    // pixel pair (r, 2p / 2p+1); fld(q,rs,cs) = (q >> (rs*32+cs*16)) & 0xffff
    float m0a=0,m0b=0,m1a=0,m1b=0,m2a=0,m2b=0,m3a=0,m3b=0,m4a=0,m4b=0;
#define FLD(q, rs, cs) ((unsigned)((q) >> ((rs) * 32 + (cs) * 16)) & 0xffffu)
#define MERGE_READ(K, RA, RB) { int u = tid + (K) * 1024; if (u < 4608) { \
        int r = u / 48, p = u - r * 48; \
        int Rp = r >> 1, rs = r & 1; \
        int Rs = (r + 1) >> 1, rss = rs ^ 1; \
        unsigned long long qaa  = Q[IAA + Rp * 48 + p]; \
        unsigned long long qas0 = Q[IAS + Rp * 49 + p]; \
        unsigned long long qas1 = Q[IAS + Rp * 49 + p + 1]; \
        unsigned long long qsa  = Q[ISA + Rs * 48 + p]; \
        unsigned long long qss0 = Q[ISS + Rs * 49 + p]; \
        unsigned long long qss1 = Q[ISS + Rs * 49 + p + 1]; \
        unsigned s0 = FLD(qaa, rs, 0) + FLD(qas0, rs, 1) + FLD(qsa, rss, 0) + FLD(qss0, rss, 1); \
        unsigned s1 = FLD(qaa, rs, 1) + FLD(qas1, rs, 0) + FLD(qsa, rss, 1) + FLD(qss1, rss, 0); \
        RA = (float)s0 * QINV; RB = (float)s1 * QINV; } }
    MERGE_READ(0, m0a, m0b)
    MERGE_READ(1, m1a, m1b)
    MERGE_READ(2, m2a, m2b)
    MERGE_READ(3, m3a, m3b)
    MERGE_READ(4, m4a, m4b)
    __syncthreads();
#define MERGE_WRITE(K, RA, RB) { int u = tid + (K) * 1024; if (u < 4608) { \
        int r = u / 48, p = u - r * 48; \
        A[r * AST + 2 * p] = RA; A[r * AST + 2 * p + 1] = RB; } }
    MERGE_WRITE(0, m0a, m0b)
    MERGE_WRITE(1, m1a, m1b)
    MERGE_WRITE(2, m2a, m2b)
    MERGE_WRITE(3, m3a, m3b)
    MERGE_WRITE(4, m4a, m4b)
    __syncthreads();

    float wreg[RAD + 1];
    make_weights(wreg);

    // ---- hconv in place: 96 rows x 8 octets = 768 units; each row's 8
    // octets live in one wave -> lockstep read-then-write is race-free ----
    if (tid < 768) {
        const int j = tid >> 3;
        const int o = (tid & 7) << 3;
        float* Ar = &A[j * AST + o];
        float Wf[40];
#pragma unroll
        for (int t = 0; t < 40; ++t) Wf[t] = Ar[t];
        float a[8] = {0, 0, 0, 0, 0, 0, 0, 0};
#pragma unroll
        for (int t = 0; t < 40; ++t) {
            float v = Wf[t];
#pragma unroll
            for (int k = 0; k < 8; ++k)
                if (t >= k && t <= k + 32)
                    a[k] += v * wreg[(t - k - 16 < 0) ? (k + 16 - t) : (t - k - 16)];
        }
#pragma unroll
        for (int k = 0; k < 8; ++k) Ar[k] = a[k];
    }
    __syncthreads();

    // ---- vconv + store: thread covers 4 rows x 1 col (16 groups x 64 cols) ----
    const int lx = tid & 63;
    const int y0 = (tid >> 6) << 2;      // 0,4,...,60
    float Wf[36];
#pragma unroll
    for (int t = 0; t < 36; ++t) Wf[t] = A[(y0 + t) * AST + lx];
    float a[4] = {0, 0, 0, 0};
#pragma unroll
    for (int t = 0; t < 36; ++t) {
        float v = Wf[t];
#pragma unroll
        for (int k = 0; k < 4; ++k)
            if (t >= k && t <= k + 32)
                a[k] += v * wreg[(t - k - 16 < 0) ? (k + 16 - t) : (t - k - 16)];
    }
    const int orow = (tI << 6) + y0, ocol = (tJ << 6) + lx;
#pragma unroll
    for (int k = 0; k < 4; ++k)
        out[(size_t)(orow + k) * WOUT + ocol] = a[k];
}

extern "C" void kernel_launch(void* const* d_in, const int* in_sizes, int n_in,
                              void* d_out, int out_size, void* d_ws, size_t ws_size,
                              hipStream_t stream) {
    const float2* pos   = (const float2*)d_in[0];   // (N,2) as (x,y)
    const float*  inten = (const float*)d_in[1];
    int n = in_sizes[1];

    ushort4* bins   = (ushort4*)d_ws;                                   // 1024*2560*8 = 21.0 MB
    int*     cursor = (int*)((char*)d_ws + (size_t)NBIN * CAP * sizeof(ushort4));

    hipMemsetAsync(cursor, 0, NBIN * sizeof(int), stream);
    scatter_kernel<<<NBLK, THR, 0, stream>>>(pos, inten, cursor, bins, n);
    splat_conv<<<NBIN, 1024, 0, stream>>>(bins, cursor, (float*)d_out);
}

// Round 11
// 109.039 us; speedup vs baseline: 1.0796x; 1.0796x over previous
//
#include <hip/hip_runtime.h>
#include <hip/hip_fp16.h>
#include <math.h>

#define HP   2080          // padded height (2048 + 2*16)
#define WP   2080          // padded width
#define MARG 16
#define HOUT 2048
#define WOUT 2048
#define RAD  16            // truncation radius; tail mass ~2e-7

#define TGRID 32           // 32x32 output tiles of 64x64
#define NBIN  1024         // one bin per output tile
#define CAP   2560         // records per tile (mean ~2248, +6 sigma)

// scatter shape: 256 blocks = 1/CU, ~9.4K records/block -> per-(block,bin)
// runs ~9.2 records = 74B
#define NBLK 256
#define THR  1024
#define PPT  4             // 256*1024*4 = 1,048,576 >= N
#define RCAP 10240         // per-block record slots (mean ~9410, +11 sigma)

#define AST  97            // f32 frame stride (96 + 1 pad)
#define INV  0xffffffffu

#define FSCALE    33554432.0f            // 2^25 fixed-point scale
#define FINVSCALE 2.9802322387695312e-8f // 2^-25

// exact discrete tap via Poisson summation: g[n] = sqrt(pi/200)*exp(-pi^2 n^2/200)
__device__ __forceinline__ void make_weights(float* wreg) {
#pragma unroll
    for (int t = 0; t <= RAD; ++t)
        wreg[t] = 0.12533141373155003f * __expf(-0.04934802200544679f * (float)(t * t));
}

// ---------------------------------------------------------------------------
// pass 1 (round-9 verbatim): duplicate each point into every output tile
// whose 96x96 conv frame it touches; histogram atomicAdd return value IS the
// rank; global cursor reservation issued BEFORE the scan (latency hides);
// LDS-sort by bin; coalesced copy-out in ~74B runs.
// ---------------------------------------------------------------------------
__global__ __launch_bounds__(THR) void scatter_kernel(const float2* __restrict__ pos,
                                                      const float* __restrict__ inten,
                                                      int* __restrict__ cursor,   // [NBIN], zeroed
                                                      ushort4* __restrict__ bins,
                                                      int n) {
    __shared__ int     lhist[NBIN];
    __shared__ int     lofs[NBIN];
    __shared__ int     lbase[NBIN];
    __shared__ int     wsum[16];
    __shared__ int     stot;
    __shared__ ushort4 lrec[RCAP];   // 80 KB
    __shared__ ushort  lbin[RCAP];   // 20 KB

    const int tid = threadIdx.x;
    lhist[tid] = 0;                  // THR == NBIN
    __syncthreads();

    const int stride = NBLK * THR;
    const int start  = blockIdx.x * THR + tid;
    unsigned ra[PPT], rb[PPT], rc[PPT];
    unsigned p0[PPT], p1[PPT], p2[PPT], p3[PPT];   // (bin<<16)|rank, statically indexed

#pragma unroll
    for (int it = 0; it < PPT; ++it) {
        int i = start + it * stride;
        p0[it] = p1[it] = p2[it] = p3[it] = INV;
        ra[it] = 0;
        if (i < n) {
            float2 p = pos[i];
            float I  = inten[i];
            float px = p.x + MARG, py = p.y + MARG;
            int col = (int)floorf(px), row = (int)floorf(py);
            row = min(max(row, 0), HP - 1);
            col = min(max(col, 0), WP - 1);
            float dy = py - (float)row, dx = px - (float)col;
            ra[it] = ((unsigned)row << 12) | (unsigned)col;
            rb[it] = (unsigned)__half_as_ushort(__float2half(dx))
                   | ((unsigned)__half_as_ushort(__float2half(dy)) << 16);
            rc[it] = (unsigned)__half_as_ushort(__float2half(I));
            int tIlo = max(0, ((row + 32) >> 6) - 1), tIhi = min(TGRID - 1, (row + 1) >> 6);
            int tJlo = max(0, ((col + 32) >> 6) - 1), tJhi = min(TGRID - 1, (col + 1) >> 6);
            int b00 = (tIlo << 5) | tJlo;
            p0[it] = ((unsigned)b00 << 16) | (unsigned)atomicAdd(&lhist[b00], 1);
            if (tJhi > tJlo) {
                int b = (tIlo << 5) | tJhi;
                p1[it] = ((unsigned)b << 16) | (unsigned)atomicAdd(&lhist[b], 1);
            }
            if (tIhi > tIlo) {
                int b = (tIhi << 5) | tJlo;
                p2[it] = ((unsigned)b << 16) | (unsigned)atomicAdd(&lhist[b], 1);
                if (tJhi > tJlo) {
                    int b2 = (tIhi << 5) | tJhi;
                    p3[it] = ((unsigned)b2 << 16) | (unsigned)atomicAdd(&lhist[b2], 1);
                }
            }
        }
    }
    __syncthreads();

    // ---- global reservation FIRST (latency hides under the scan) ----
    int c = lhist[tid];
    int gbase = (c > 0) ? atomicAdd(&cursor[tid], c) : 0;

    // ---- exclusive scan, exactly 1 bin per thread ----
    int incl = c;
    for (int d = 1; d < 64; d <<= 1) {
        int u = __shfl_up(incl, d, 64);
        if ((tid & 63) >= d) incl += u;
    }
    if ((tid & 63) == 63) wsum[tid >> 6] = incl;
    __syncthreads();
    if (tid == 0) {
        int s = 0;
        for (int w = 0; w < 16; ++w) { int x = wsum[w]; wsum[w] = s; s += x; }
        stot = s;
    }
    __syncthreads();
    lofs[tid]  = incl - c + wsum[tid >> 6];
    lbase[tid] = gbase;
    __syncthreads();

    // ---- place records into LDS by bin using the saved ranks (no atomics) ----
#pragma unroll
    for (int it = 0; it < PPT; ++it) {
        const int row = (int)(ra[it] >> 12), col = (int)(ra[it] & 4095u);
        ushort4 rec;
        rec.y = (unsigned short)(rb[it] & 0xffffu);
        rec.z = (unsigned short)(rb[it] >> 16);
        rec.w = (unsigned short)rc[it];
        auto place = [&](unsigned pv) {
            if (pv != INV) {
                int bin  = (int)(pv >> 16);
                int rank = (int)(pv & 0xffffu);
                int fr1  = row - ((bin >> 5) << 6) + 1;   // 0..96
                int fc1  = col - ((bin & 31) << 6) + 1;   // 0..96
                int slot = lofs[bin] + rank;
                if (slot < RCAP) {
                    rec.x = (unsigned short)((fr1 << 7) | fc1);
                    lrec[slot] = rec;
                    lbin[slot] = (unsigned short)bin;
                }
            }
        };
        place(p0[it]); place(p1[it]); place(p2[it]); place(p3[it]);
    }
    __syncthreads();

    // ---- coalesced copy-out ----
    const int total = min(stot, RCAP);
    for (int j = tid; j < total; j += THR) {
        int b = lbin[j];
        int g = lbase[b] + (j - lofs[b]);
        if (g < CAP) bins[(size_t)b * CAP + g] = lrec[j];
    }
}

// ---------------------------------------------------------------------------
// pass 2 (round-9 dual-parity splat, restored): each record's 2x2 tap block
// = 2 rows x 1 column-pair. Frames hold u64 cells = two Q7.25 halves:
//   even pairs p=0..47  cover cols (2p, 2p+1)      at U[r*97 + p]
//   odd  pairs q=0..48  cover cols (2q-1, 2q)      at U[r*97 + 48 + q]
// -> exactly 2 atomicAdd(u64) per record. Merge converts to f32 in place,
// then hconv in place + vconv (8 rows/thread) + non-temporal store.
// ---------------------------------------------------------------------------
__device__ __forceinline__ void splat_rec(ushort4 r, unsigned long long* U) {
    int fr1 = r.x >> 7, fc1 = r.x & 127;              // 0..96 each
    float dx = __half2float(__ushort_as_half(r.y));
    float dy = __half2float(__ushort_as_half(r.z));
    float I  = __half2float(__ushort_as_half(r.w));
    float wy1 = dy * I, wy0 = I - wy1;
    float wl, wh; int k;
    if (fc1 & 1) { k = fc1 >> 1;        wl = 1.0f - dx; wh = dx; }                 // even pair
    else {         k = 48 + (fc1 >> 1); wl = (fc1 >= 1) ? 1.0f - dx : 0.0f;        // odd pair
                                        wh = (fc1 <= 95) ? dx : 0.0f; }
    if (fr1 >= 1) {
        unsigned long long v = ((unsigned long long)(unsigned)(wy0 * wh * FSCALE) << 32)
                             |  (unsigned long long)(unsigned)(wy0 * wl * FSCALE);
        atomicAdd(&U[(fr1 - 1) * 97 + k], v);
    }
    if (fr1 <= 95) {
        unsigned long long v = ((unsigned long long)(unsigned)(wy1 * wh * FSCALE) << 32)
                             |  (unsigned long long)(unsigned)(wy1 * wl * FSCALE);
        atomicAdd(&U[fr1 * 97 + k], v);
    }
}

__global__ __launch_bounds__(1024) void splat_conv(const ushort4* __restrict__ bins,
                                                   const int* __restrict__ cursor,
                                                   float* __restrict__ out) {
    __shared__ unsigned long long U[96 * 97];   // 74.5 KB dual-parity frames
    float* A = (float*)U;                        // merged f32 frame [96][AST]
    const int tid = threadIdx.x;
    const int b  = blockIdx.x;
    const int tI = b >> 5, tJ = b & 31;

    // prefetch this tile's records (<=3/thread) BEFORE zeroing
    const int cnt = min(cursor[b], CAP);
    const ushort4* bp = bins + (size_t)b * CAP;
    const bool h0 = tid < cnt, h1 = tid + 1024 < cnt, h2 = tid + 2048 < cnt;
    ushort4 r0_ = {0,0,0,0}, r1_ = {0,0,0,0}, r2_ = {0,0,0,0};
    if (h0) r0_ = bp[tid];
    if (h1) r1_ = bp[tid + 1024];
    if (h2) r2_ = bp[tid + 2048];

    uint4* U4 = (uint4*)U;                       // 9312 u64 = 4656 uint4
    for (int i = tid; i < 4656; i += 1024) U4[i] = make_uint4(0u, 0u, 0u, 0u);
    __syncthreads();

    if (h0) splat_rec(r0_, U);
    if (h1) splat_rec(r1_, U);
    if (h2) splat_rec(r2_, U);
    __syncthreads();

    // ---- merge u64 parities -> f32 frame (in place, register-staged) ----
    float m0a=0,m0b=0,m1a=0,m1b=0,m2a=0,m2b=0,m3a=0,m3b=0,m4a=0,m4b=0;
#define MERGE_READ(K, RA, RB) { int u = tid + (K) * 1024; if (u < 4608) { \
        int r = u / 48, cp = u - r * 48; \
        unsigned long long e  = U[r * 97 + cp]; \
        unsigned long long ol = U[r * 97 + 48 + cp]; \
        unsigned long long orr= U[r * 97 + 48 + cp + 1]; \
        RA = ((float)(unsigned)e         + (float)(unsigned)(ol >> 32)) * FINVSCALE; \
        RB = ((float)(unsigned)(e >> 32) + (float)(unsigned)orr)        * FINVSCALE; } }
    MERGE_READ(0, m0a, m0b)
    MERGE_READ(1, m1a, m1b)
    MERGE_READ(2, m2a, m2b)
    MERGE_READ(3, m3a, m3b)
    MERGE_READ(4, m4a, m4b)
    __syncthreads();
#define MERGE_WRITE(K, RA, RB) { int u = tid + (K) * 1024; if (u < 4608) { \
        int r = u / 48, cp = u - r * 48; \
        A[r * AST + 2 * cp] = RA; A[r * AST + 2 * cp + 1] = RB; } }
    MERGE_WRITE(0, m0a, m0b)
    MERGE_WRITE(1, m1a, m1b)
    MERGE_WRITE(2, m2a, m2b)
    MERGE_WRITE(3, m3a, m3b)
    MERGE_WRITE(4, m4a, m4b)
    __syncthreads();

    float wreg[RAD + 1];
    make_weights(wreg);

    // ---- hconv in place: 96 rows x 8 octets = 768 units; each row's 8
    // octets live in one wave -> lockstep read-then-write is race-free ----
    if (tid < 768) {
        const int j = tid >> 3;
        const int o = (tid & 7) << 3;
        float* Ar = &A[j * AST + o];
        float Wf[40];
#pragma unroll
        for (int t = 0; t < 40; ++t) Wf[t] = Ar[t];
        float a[8] = {0, 0, 0, 0, 0, 0, 0, 0};
#pragma unroll
        for (int t = 0; t < 40; ++t) {
            float v = Wf[t];
#pragma unroll
            for (int k = 0; k < 8; ++k)
                if (t >= k && t <= k + 32)
                    a[k] += v * wreg[(t - k - 16 < 0) ? (k + 16 - t) : (t - k - 16)];
        }
#pragma unroll
        for (int k = 0; k < 8; ++k) Ar[k] = a[k];
    }
    __syncthreads();

    // ---- vconv + nt store: 8 rows x 1 col per thread (512 active; idle
    // waves exit early, co-resident block fills the SIMD) ----
    if (tid < 512) {
        const int lx = tid & 63;
        const int y0 = (tid >> 6) << 3;      // 0,8,...,56
        float Wf[40];
#pragma unroll
        for (int t = 0; t < 40; ++t) Wf[t] = A[(y0 + t) * AST + lx];
        float a[8] = {0, 0, 0, 0, 0, 0, 0, 0};
#pragma unroll
        for (int t = 0; t < 40; ++t) {
            float v = Wf[t];
#pragma unroll
            for (int k = 0; k < 8; ++k)
                if (t >= k && t <= k + 32)
                    a[k] += v * wreg[(t - k - 16 < 0) ? (k + 16 - t) : (t - k - 16)];
        }
        const int orow = (tI << 6) + y0, ocol = (tJ << 6) + lx;
#pragma unroll
        for (int k = 0; k < 8; ++k)
            __builtin_nontemporal_store(a[k], &out[(size_t)(orow + k) * WOUT + ocol]);
    }
}

extern "C" void kernel_launch(void* const* d_in, const int* in_sizes, int n_in,
                              void* d_out, int out_size, void* d_ws, size_t ws_size,
                              hipStream_t stream) {
    const float2* pos   = (const float2*)d_in[0];   // (N,2) as (x,y)
    const float*  inten = (const float*)d_in[1];
    int n = in_sizes[1];

    ushort4* bins   = (ushort4*)d_ws;                                   // 1024*2560*8 = 21.0 MB
    int*     cursor = (int*)((char*)d_ws + (size_t)NBIN * CAP * sizeof(ushort4));

    hipMemsetAsync(cursor, 0, NBIN * sizeof(int), stream);
    scatter_kernel<<<NBLK, THR, 0, stream>>>(pos, inten, cursor, bins, n);
    splat_conv<<<NBIN, 1024, 0, stream>>>(bins, cursor, (float*)d_out);
}